// Round 11
// baseline (315.267 us; speedup 1.0000x reference)
//
#include <hip/hip_runtime.h>
#include <cstdint>
#include <cstddef>

typedef unsigned short u16;
typedef __bf16 bf16x8 __attribute__((ext_vector_type(8)));
typedef float f32x4 __attribute__((ext_vector_type(4)));
typedef unsigned int u32x4 __attribute__((ext_vector_type(4)));
typedef unsigned int u32x2 __attribute__((ext_vector_type(2)));
typedef u16 u16x4 __attribute__((ext_vector_type(4)));

typedef __attribute__((address_space(3))) void lds_void;
typedef __attribute__((address_space(1))) void glb_void;

constexpr float CEXP = 92.33248261689366f;   // 64 * log2(e): folded into Q

// ---------------- workspace layout (u16 element offsets) ----------------
constexpr size_t XSZ = 4096ull * 1024ull;   // one [4096,1024] bf16 array
constexpr size_t WSZ = 1024ull * 1024ull;   // one [1024,1024] bf16 array
constexpr size_t OFF_WQH = 0;
constexpr size_t OFF_WQL = OFF_WQH + WSZ;
constexpr size_t OFF_WKH = OFF_WQL + WSZ;
constexpr size_t OFF_WKL = OFF_WKH + WSZ;
constexpr size_t OFF_WVH = OFF_WKL + WSZ;
constexpr size_t OFF_WVL = OFF_WVH + WSZ;   // UNUSED (layout stability)
constexpr size_t OFF_QH  = OFF_WVL + WSZ;   // [B,H,S,64]  (pre-scaled by CEXP)
constexpr size_t OFF_QL  = OFF_QH + XSZ;
constexpr size_t OFF_KH  = OFF_QL + XSZ;
constexpr size_t OFF_KL  = OFF_KH + XSZ;
constexpr size_t OFF_VT  = OFF_KL + XSZ;    // [B,H,64,S]

// ---------------- helpers ----------------
__device__ __forceinline__ u16 f2b(float f) {           // fp32 -> bf16 RNE
  unsigned u = __builtin_bit_cast(unsigned, f);
  return (u16)((u + 0x7FFFu + ((u >> 16) & 1u)) >> 16);
}
__device__ __forceinline__ float b2f(u16 h) {
  return __builtin_bit_cast(float, ((unsigned)h) << 16);
}
__device__ __forceinline__ float bitf(unsigned u) {
  return __builtin_bit_cast(float, u);
}
__device__ __forceinline__ bf16x8 ld8(const u16* p) {   // 16B frag load
  return __builtin_bit_cast(bf16x8, *(const u32x4*)p);
}
__device__ __forceinline__ unsigned pk2(float a, float b) {  // pack 2 bf16 (RNE)
#if __has_builtin(__builtin_amdgcn_cvt_pk_bf16_f32)
  auto v = __builtin_amdgcn_cvt_pk_bf16_f32(a, b);
  return __builtin_bit_cast(unsigned, v);
#else
  return (unsigned)f2b(a) | ((unsigned)f2b(b) << 16);
#endif
}
__device__ __forceinline__ float ex2(float x) {         // raw v_exp_f32
#if __has_builtin(__builtin_amdgcn_exp2f)
  return __builtin_amdgcn_exp2f(x);
#else
  return exp2f(x);
#endif
}
__device__ __forceinline__ void glds16(const void* g, void* l) { // 16B global->LDS
  __builtin_amdgcn_global_load_lds((const glb_void*)g, (lds_void*)l, 16, 0, 0);
}
// swizzled LDS offset for a [rows][32 u16] tile: chunk = 8 u16 (16B)
__device__ __forceinline__ int swz32(int row, int cg) {
  return row * 32 + ((cg ^ ((row >> 1) & 3)) * 8);
}
// swizzled LDS offset for a [rows][64 u16] tile: chunk = 8 u16 (16B)
__device__ __forceinline__ int swz64(int row, int cg) {
  return row * 64 + ((cg ^ (row & 7)) * 8);
}

// ---------------- convert: W^T (hi/lo) only ----------------
// x-path deleted (gemm stages fp32 X directly). W path: transpose + hi/lo.
__global__ __launch_bounds__(256) void convert_w(const float* __restrict__ Wq,
                                                 const float* __restrict__ Wk,
                                                 const float* __restrict__ Wv,
                                                 u16* __restrict__ ws) {
  __shared__ float tile[32][33];
  int id = blockIdx.x;
  int t = threadIdx.x;
  int z = id >> 10, rem = id & 1023;
  const float* W = (z == 0) ? Wq : (z == 1) ? Wk : Wv;
  u16* hiT = ws + ((z == 0) ? OFF_WQH : (z == 1) ? OFF_WKH : OFF_WVH);
  u16* loT = ws + ((z == 0) ? OFF_WQL : (z == 1) ? OFF_WKL : OFF_WVL);
  int n0 = (rem & 31) * 32, k0 = (rem >> 5) * 32;
  int r = t >> 3, c0 = (t & 7) * 4;
  float4 vv = *(const float4*)(W + (size_t)(k0 + r) * 1024 + n0 + c0);
  tile[r][c0] = vv.x; tile[r][c0 + 1] = vv.y; tile[r][c0 + 2] = vv.z; tile[r][c0 + 3] = vv.w;
  __syncthreads();
  u16x4 hv, lv;
#pragma unroll
  for (int j = 0; j < 4; ++j) {
    float x = tile[c0 + j][r];          // = W[k0+c0+j][n0+r]
    u16 hb = f2b(x);
    hv[j] = hb;
    lv[j] = f2b(x - b2f(hb));
  }
  size_t o = (size_t)(n0 + r) * 1024 + k0 + c0;
  *(u16x4*)(hiT + o) = hv;
  if (z != 2) *(u16x4*)(loT + o) = lv;
}

// ---------------- QKV projection GEMM, 128x128 tile, 4 waves -----------------
// R18: attn-R16-style pipelined k-loop:
//   [compute kb]  bar  [commit kb+1 (reg->LDS, incl. fp32->bf16 hi/lo conv)]
//   bar  [issue kb+2 global loads -> regs]
// Removes the per-k-step vmcnt(0) drain (loads get a full compute phase to
// land) and converts each A element ONCE write-side (was 2x read-side).
// Staging thread t owns row t&127, k-half t>>7; LDS layout/compute section
// identical to the proven R14 bf16 path (swz32 ld8 frags).
__global__ __launch_bounds__(256, 3) void gemm_qkv(u16* __restrict__ ws,
                                                   const float* __restrict__ xq,
                                                   const float* __restrict__ xk,
                                                   const float* __restrict__ xv) {
  __shared__ u16 smem[16384];          // 32 KB
  u16* sAh = smem;                     // [128*32] bf16 hi (8 KB)
  u16* sAl = smem + 4096;              // lo (8 KB)
  u16* sBh = smem + 8192;              // 8 KB
  u16* sBl = smem + 12288;             // 8 KB
  u16* cbuf = smem;                    // 128x128 u16 epilogue view (32 KB)

  int id = blockIdx.x;
  int xcd = id & 7, seq = id >> 3;          // seq 0..95
  int pair = (seq >> 3) * 8 + xcd;          // 0..95, z-balanced per XCD
  int tile_n = seq & 7;
  int z = pair >> 5;                        // 0..2
  int tile_m = pair & 31;

  const float* X = (z == 0) ? xq : (z == 1) ? xk : xv;
  const u16 *Bh, *Bl; u16 *Oh, *Ol; bool split;
  if (z == 0)      { Bh = ws + OFF_WQH; Bl = ws + OFF_WQL; Oh = ws + OFF_QH; Ol = ws + OFF_QL; split = true; }
  else if (z == 1) { Bh = ws + OFF_WKH; Bl = ws + OFF_WKL; Oh = ws + OFF_KH; Ol = ws + OFF_KL; split = true; }
  else             { Bh = ws + OFF_WVH; Bl = nullptr;      Oh = ws + OFF_VT; Ol = nullptr;    split = false; }
  float oscale = (z == 0) ? CEXP : 1.0f;
  int m0 = tile_m * 128, n0 = tile_n * 128;
  int t = threadIdx.x, lane = t & 63, wave = t >> 6;
  int quad = lane >> 4, l15 = lane & 15;
  int wm = (wave >> 1) * 64, wn = (wave & 1) * 64;
  f32x4 acc[4][4] = {};

  // ---- staging decomposition: row sr (0..127), k-half skh (0,1) ----
  int sr = t & 127, skh = t >> 7;
  const float* aSrc = X + (size_t)(m0 + sr) * 1024 + skh * 16;
  const u16* bhSrc = Bh + (size_t)(n0 + sr) * 1024 + skh * 16;
  const u16* blSrc = split ? (Bl + (size_t)(n0 + sr) * 1024 + skh * 16) : nullptr;
  int so0 = swz32(sr, skh * 2), so1 = swz32(sr, skh * 2 + 1);  // chunk slots

  float4 xa[4]; u32x4 xbh[2], xbl[2];
  auto issue = [&](int kb) {
    const float* ap = aSrc + kb * 32;
#pragma unroll
    for (int i = 0; i < 4; ++i) xa[i] = *(const float4*)(ap + i * 4);
    const u16* bp = bhSrc + kb * 32;
    xbh[0] = *(const u32x4*)(bp);
    xbh[1] = *(const u32x4*)(bp + 8);
    if (split) {
      const u16* lp = blSrc + kb * 32;
      xbl[0] = *(const u32x4*)(lp);
      xbl[1] = *(const u32x4*)(lp + 8);
    }
  };
  auto commit = [&]() {
    unsigned hw[8], lw[8];
#pragma unroll
    for (int p = 0; p < 8; ++p) {
      float a0 = xa[p >> 1][(p & 1) * 2];
      float a1 = xa[p >> 1][(p & 1) * 2 + 1];
      hw[p] = pk2(a0, a1);
      lw[p] = pk2(a0 - bitf(hw[p] << 16), a1 - bitf(hw[p] & 0xFFFF0000u));
    }
    *(u32x4*)(&sAh[so0]) = u32x4{hw[0], hw[1], hw[2], hw[3]};
    *(u32x4*)(&sAh[so1]) = u32x4{hw[4], hw[5], hw[6], hw[7]};
    *(u32x4*)(&sBh[so0]) = xbh[0];
    *(u32x4*)(&sBh[so1]) = xbh[1];
    if (split) {
      *(u32x4*)(&sAl[so0]) = u32x4{lw[0], lw[1], lw[2], lw[3]};
      *(u32x4*)(&sAl[so1]) = u32x4{lw[4], lw[5], lw[6], lw[7]};
      *(u32x4*)(&sBl[so0]) = xbl[0];
      *(u32x4*)(&sBl[so1]) = xbl[1];
    }
  };

  // ---- prologue: tile 0 committed, tile 1 in regs ----
  issue(0);
  commit();
  issue(1);
  __syncthreads();

  for (int kb = 0; kb < 32; ++kb) {
    // ---- compute kb (R14 bf16 frag path) ----
    bf16x8 afh[4], afl[4];
#pragma unroll
    for (int mt = 0; mt < 4; ++mt) {
      int ra = wm + mt * 16 + l15;
      afh[mt] = ld8(&sAh[swz32(ra, quad)]);
      if (split) afl[mt] = ld8(&sAl[swz32(ra, quad)]);
    }
#pragma unroll
    for (int nt = 0; nt < 4; ++nt) {
      int rb = wn + nt * 16 + l15;
      bf16x8 bfh = ld8(&sBh[swz32(rb, quad)]);
      bf16x8 bfl;
      if (split) bfl = ld8(&sBl[swz32(rb, quad)]);
#pragma unroll
      for (int mt = 0; mt < 4; ++mt) {
        acc[mt][nt] = __builtin_amdgcn_mfma_f32_16x16x32_bf16(afh[mt], bfh, acc[mt][nt], 0, 0, 0);
        if (split) {
          acc[mt][nt] = __builtin_amdgcn_mfma_f32_16x16x32_bf16(afl[mt], bfh, acc[mt][nt], 0, 0, 0);
          acc[mt][nt] = __builtin_amdgcn_mfma_f32_16x16x32_bf16(afh[mt], bfl, acc[mt][nt], 0, 0, 0);
        }
      }
    }
    // ---- barrier-locked commit of tile kb+1 ----
    __syncthreads();
    if (kb < 31) commit();
    __syncthreads();
    // ---- issue tile kb+2 ----
    if (kb < 30) issue(kb + 2);
  }

  // ---- LDS-staged coalesced epilogue (cbuf aliases staging; bar above) ----
  auto epi_round = [&](u16* dst, bool lo_round) {
#pragma unroll
    for (int mt = 0; mt < 4; ++mt)
#pragma unroll
      for (int nt = 0; nt < 4; ++nt)
#pragma unroll
        for (int r = 0; r < 4; ++r) {
          int row = wm + mt * 16 + quad * 4 + r;
          int col = wn + nt * 16 + l15;
          float v = acc[mt][nt][r] * oscale;
          u16 hb = f2b(v);
          u16 val = lo_round ? f2b(v - b2f(hb)) : hb;
          cbuf[row * 128 + (((col >> 3) ^ (row & 15)) * 8) + (col & 7)] = val;
        }
    __syncthreads();
#pragma unroll
    for (int rr = 0; rr < 2; ++rr) {
      int row = rr * 64 + (t >> 2), seg = t & 3;
      int gm = m0 + row, bb = gm >> 11, s = gm & 2047;
      int hh = (n0 >> 6) + (seg >> 1), d0 = (seg & 1) * 32;
      u16* gp = dst + ((size_t)(bb * 16 + hh) * 2048 + s) * 64 + d0;
#pragma unroll
      for (int i = 0; i < 4; ++i) {
        int phys = (seg * 4 + i) ^ (row & 15);
        *(u32x4*)(gp + i * 8) = *(const u32x4*)(&cbuf[row * 128 + phys * 8]);
      }
    }
  };
  __syncthreads();                 // all waves done with staging reads
  if (split) {
    epi_round(Oh, false);
    __syncthreads();
    epi_round(Ol, true);
  } else {
    // ---- V: transposed epilogue, writes VT[b,h,d,s] directly ----
#pragma unroll
    for (int mt = 0; mt < 4; ++mt)
#pragma unroll
      for (int nt = 0; nt < 4; ++nt)
#pragma unroll
        for (int r = 0; r < 4; ++r) {
          int row = wm + mt * 16 + quad * 4 + r;       // seq within tile 0..127
          int col = wn + nt * 16 + l15;                // dim within 128 (2 heads)
          cbuf[row * 128 + (((col >> 3) ^ (row & 15)) * 8) + (col & 7)] =
              f2b(acc[mt][nt][r]);
        }
    __syncthreads();
    int col = t >> 1, sh = t & 1;
    int hg = (n0 + col) >> 6, d = (n0 + col) & 63;
    int bb = m0 >> 11, s0 = m0 & 2047;
#pragma unroll
    for (int part = 0; part < 2; ++part) {
      u16 vals[32];
#pragma unroll
      for (int i = 0; i < 32; ++i) {
        int row = part * 64 + sh * 32 + i;
        vals[i] = cbuf[row * 128 + (((col >> 3) ^ (row & 15)) * 8) + (col & 7)];
      }
      u16* gp = Oh + ((size_t)((bb * 16 + hg) * 64 + d)) * 2048 + s0 + part * 64 + sh * 32;
#pragma unroll
      for (int i = 0; i < 4; ++i)
        *(u32x4*)(gp + i * 8) = *(const u32x4*)(&vals[i * 8]);
    }
  }
}

// ---------------- flash attention: 64 Q-rows/block, 64-key tiles -------------
// R16 (unchanged, measured 93.9 us): barriers bracket only the LDS commit;
// V double-buffered; SM+PV+next-QK unsynchronized. XCD head-grouping,
// dead-tile skip, defer-rescale, swapped PV, max3 tree, T14 reg-prefetch.
__global__ __launch_bounds__(256, 4) void attn(const u16* __restrict__ ws,
                                               float* __restrict__ out) {
  __shared__ u16 lkh[64 * 64];
  __shared__ u16 lkl[64 * 64];
  __shared__ u16 lvt[2][64 * 64];    // double-buffered V
  __shared__ u16 lp[4][16 * 64];     // per-wave P tile [qrow][key], swz64
  const u16* Qh = ws + OFF_QH; const u16* Ql = ws + OFF_QL;
  const u16* Kh = ws + OFF_KH; const u16* Kl = ws + OFF_KL;
  const u16* Vt = ws + OFF_VT;
  // ---- XCD-grouped decode: xcd owns heads [xcd*4, xcd*4+4) ----
  int id = blockIdx.x;
  int xcd = id & 7, slot = id >> 3;            // slot 0..127
  int hh = xcd * 4 + (slot >> 5);              // 0..31  (b*16+h)
  int q0 = (slot & 31) * 64;
  int b = hh >> 4, h = hh & 15;
  int t = threadIdx.x, lane = t & 63, wave = t >> 6;
  int quad = lane >> 4, l15 = lane & 15;
  size_t hb = (size_t)hh * (2048 * 64);
  bf16x8 onesf;                                  // ones A-frag for row-sum MFMA
#pragma unroll
  for (int j = 0; j < 8; ++j) onesf[j] = __builtin_bit_cast(__bf16, (u16)0x3F80);
  int qrow = q0 + wave * 16 + l15;
  bf16x8 qfh[2], qfl[2];
#pragma unroll
  for (int ks = 0; ks < 2; ++ks) {
    size_t qo = hb + (size_t)qrow * 64 + ks * 32 + quad * 8;
    qfh[ks] = ld8(Qh + qo);
    qfl[ks] = ld8(Ql + qo);
  }
  float mi = -1e30f;                 // running max for qrow=l15
  f32x4 lsum = {};                   // row-sum accumulator (all 4 regs equal)
  f32x4 o[4] = {};                   // o^T: col=l15=qrow, row=d
  int rl = lane >> 3, cgl = lane & 7;            // staging: 8 rows x 8 chunks/issue

  size_t aK[2], aV[2]; int lb[2];
#pragma unroll
  for (int i = 0; i < 2; ++i) {
    int row = wave * 16 + i * 8 + rl;            // tile-local row 0..63
    int cgg = cgl ^ (row & 7);
    aK[i] = hb + (size_t)row * 64 + cgg * 8;     // + kt*4096 in-loop
    aV[i] = hb + (size_t)row * 2048 + cgg * 8;   // + kt*64  in-loop
    lb[i] = (wave * 16 + i * 8) * 64;
  }
  int soF[2][4];
#pragma unroll
  for (int ks = 0; ks < 2; ++ks)
#pragma unroll
    for (int nt = 0; nt < 4; ++nt)
      soF[ks][nt] = swz64(nt * 16 + l15, ks * 4 + quad);
  int soP[4];
  {
    int r7 = l15 & 7;
#pragma unroll
    for (int nt = 0; nt < 4; ++nt) {
      int c = nt * 2 + (quad >> 1);
      soP[nt] = l15 * 64 + ((c ^ r7) * 8) + (quad & 1) * 4;
    }
  }
  int soPa[2];
#pragma unroll
  for (int ks = 0; ks < 2; ++ks) soPa[ks] = swz64(l15, ks * 4 + quad);
  u16* lpw = &lp[wave][0];

  // ---- prologue: stage tile 0 via global_load_lds; prefetch tile 1 regs ----
#pragma unroll
  for (int i = 0; i < 2; ++i) {
    glds16(Kh + aK[i], &lkh[lb[i]]);
    glds16(Kl + aK[i], &lkl[lb[i]]);
    glds16(Vt + aV[i], &lvt[0][lb[i]]);
  }
  u32x4 pk_[2], pl_[2], pv_[2];
#pragma unroll
  for (int i = 0; i < 2; ++i) {
    pk_[i] = *(const u32x4*)(Kh + aK[i] + 4096);
    pl_[i] = *(const u32x4*)(Kl + aK[i] + 4096);
    pv_[i] = *(const u32x4*)(Vt + aV[i] + 64);
  }
  __syncthreads();

  for (int kt = 0; kt < 32; ++kt) {
    // ---- phase A: QK^T (swapped): sc[nt] rows=keys, col=qrow=l15 ----
    f32x4 sc[4] = {};
    __builtin_amdgcn_s_setprio(1);
#pragma unroll
    for (int nt = 0; nt < 4; ++nt) {
#pragma unroll
      for (int ks = 0; ks < 2; ++ks) {
        bf16x8 kh_ = ld8(&lkh[soF[ks][nt]]);
        bf16x8 kl_ = ld8(&lkl[soF[ks][nt]]);
        sc[nt] = __builtin_amdgcn_mfma_f32_16x16x32_bf16(kh_, qfh[ks], sc[nt], 0, 0, 0);
        sc[nt] = __builtin_amdgcn_mfma_f32_16x16x32_bf16(kl_, qfh[ks], sc[nt], 0, 0, 0);
        sc[nt] = __builtin_amdgcn_mfma_f32_16x16x32_bf16(kh_, qfl[ks], sc[nt], 0, 0, 0);
      }
    }
    __builtin_amdgcn_s_setprio(0);
    // ---- barrier-locked commit (the ONLY synchronized region) ----
    __syncthreads();
    if (kt < 31) {
#pragma unroll
      for (int i = 0; i < 2; ++i) {
        *(u32x4*)(&lkh[lb[i] + lane * 8]) = pk_[i];
        *(u32x4*)(&lkl[lb[i] + lane * 8]) = pl_[i];
        *(u32x4*)(&lvt[(kt + 1) & 1][lb[i] + lane * 8]) = pv_[i];
      }
    }
    __syncthreads();
    // ---- prefetch tile kt+2 into regs (consumed at next commit) ----
    if (kt < 30) {
#pragma unroll
      for (int i = 0; i < 2; ++i) {
        pk_[i] = *(const u32x4*)(Kh + aK[i] + (kt + 2) * 4096);
        pl_[i] = *(const u32x4*)(Kl + aK[i] + (kt + 2) * 4096);
        pv_[i] = *(const u32x4*)(Vt + aV[i] + (kt + 2) * 64);
      }
    }
    // ---- phase B (unsynchronized): softmax + PV on lvt[kt&1] ----
    float t0 = fmaxf(fmaxf(sc[0][0], sc[0][1]), sc[0][2]);
    float t1 = fmaxf(fmaxf(sc[0][3], sc[1][0]), sc[1][1]);
    float t2 = fmaxf(fmaxf(sc[1][2], sc[1][3]), sc[2][0]);
    float t3 = fmaxf(fmaxf(sc[2][1], sc[2][2]), sc[2][3]);
    float t4 = fmaxf(fmaxf(sc[3][0], sc[3][1]), sc[3][2]);
    float mx = fmaxf(fmaxf(fmaxf(t0, t1), fmaxf(t2, t3)), fmaxf(t4, sc[3][3]));
    mx = fmaxf(mx, __shfl_xor(mx, 16));
    mx = fmaxf(mx, __shfl_xor(mx, 32));
    float mi_old = mi;
    unsigned long long live = __ballot(mx > mi_old - 28.0f);
    float mn = fmaxf(mi_old, mx);
    mi = mn;
    if (live) {
      unsigned long long grew = __ballot(mx > mi_old);   // wave-uniform
      // ---- P = exp2(sc - mn), packed ds_write_b64 into lp[qrow][key] ----
#pragma unroll
      for (int nt = 0; nt < 4; ++nt) {
        unsigned u01 = pk2(ex2(sc[nt][0] - mn), ex2(sc[nt][1] - mn));
        unsigned u23 = pk2(ex2(sc[nt][2] - mn), ex2(sc[nt][3] - mn));
        *(u32x2*)(&lpw[soP[nt]]) = u32x2{u01, u23};
      }
      // ---- rescale (alpha per-lane: qrow=l15 domain) ----
      if (grew) {
        float a = ex2(mi_old - mn);
#pragma unroll
        for (int r = 0; r < 4; ++r) {
          lsum[r] *= a;
          o[0][r] *= a; o[1][r] *= a; o[2][r] *= a; o[3][r] *= a;
        }
      }
      // wave-private LDS write->read: drain DS queue (in-order per wave)
      asm volatile("s_waitcnt lgkmcnt(0)" ::: "memory");
      // ---- swapped PV: o^T += V-frag (A) x P (B); lsum via ones-A ----
      bf16x8 pa[2];
#pragma unroll
      for (int ks = 0; ks < 2; ++ks) pa[ks] = ld8(&lpw[soPa[ks]]);
      __builtin_amdgcn_s_setprio(1);
      lsum = __builtin_amdgcn_mfma_f32_16x16x32_bf16(onesf, pa[0], lsum, 0, 0, 0);
      lsum = __builtin_amdgcn_mfma_f32_16x16x32_bf16(onesf, pa[1], lsum, 0, 0, 0);
      const u16* lv = &lvt[kt & 1][0];
#pragma unroll
      for (int nt = 0; nt < 4; ++nt)
#pragma unroll
        for (int ks = 0; ks < 2; ++ks) {
          bf16x8 bv = ld8(&lv[soF[ks][nt]]);
          o[nt] = __builtin_amdgcn_mfma_f32_16x16x32_bf16(bv, pa[ks], o[nt], 0, 0, 0);
        }
      __builtin_amdgcn_s_setprio(0);
    }
  }
  // epilogue: o^T -> out[b, qrow, h*64 + d], contiguous f32x4 per (nt,quad)
  float inv = 1.0f / lsum[0];
  float* op = out + (size_t)(b * 2048 + q0 + wave * 16 + l15) * 1024 + h * 64;
#pragma unroll
  for (int nt = 0; nt < 4; ++nt) {
    f32x4 w;
#pragma unroll
    for (int r = 0; r < 4; ++r) w[r] = o[nt][r] * inv;
    *(f32x4*)(op + nt * 16 + quad * 4) = w;
  }
}

extern "C" void kernel_launch(void* const* d_in, const int* in_sizes, int n_in,
                              void* d_out, int out_size, void* d_ws, size_t ws_size,
                              hipStream_t stream) {
  const float* q  = (const float*)d_in[0];
  const float* k  = (const float*)d_in[1];
  const float* v  = (const float*)d_in[2];
  const float* Wq = (const float*)d_in[3];
  const float* Wk = (const float*)d_in[4];
  const float* Wv = (const float*)d_in[5];
  u16* ws = (u16*)d_ws;
  float* out = (float*)d_out;

  convert_w<<<3072, 256, 0, stream>>>(Wq, Wk, Wv, ws);
  gemm_qkv<<<768, 256, 0, stream>>>(ws, q, k, v);
  attn<<<1024, 256, 0, stream>>>(ws, out);
}

// Round 12
// 266.315 us; speedup vs baseline: 1.1838x; 1.1838x over previous
//
#include <hip/hip_runtime.h>
#include <cstdint>
#include <cstddef>

typedef unsigned short u16;
typedef __bf16 bf16x8 __attribute__((ext_vector_type(8)));
typedef float f32x4 __attribute__((ext_vector_type(4)));
typedef unsigned int u32x4 __attribute__((ext_vector_type(4)));
typedef unsigned int u32x2 __attribute__((ext_vector_type(2)));
typedef u16 u16x4 __attribute__((ext_vector_type(4)));

typedef __attribute__((address_space(3))) void lds_void;
typedef __attribute__((address_space(1))) void glb_void;

constexpr float CEXP = 92.33248261689366f;   // 64 * log2(e): folded into Q

// ---------------- workspace layout (u16 element offsets) ----------------
constexpr size_t XSZ = 4096ull * 1024ull;   // one [4096,1024] bf16 array
constexpr size_t WSZ = 1024ull * 1024ull;   // one [1024,1024] bf16 array
constexpr size_t OFF_XQH = 0;
constexpr size_t OFF_XQL = OFF_XQH + XSZ;
constexpr size_t OFF_XKH = OFF_XQL + XSZ;
constexpr size_t OFF_XKL = OFF_XKH + XSZ;
constexpr size_t OFF_XVH = OFF_XKL + XSZ;
constexpr size_t OFF_XVL = OFF_XVH + XSZ;   // UNUSED (layout stability)
constexpr size_t OFF_WQH = OFF_XVL + XSZ;
constexpr size_t OFF_WQL = OFF_WQH + WSZ;
constexpr size_t OFF_WKH = OFF_WQL + WSZ;
constexpr size_t OFF_WKL = OFF_WKH + WSZ;
constexpr size_t OFF_WVH = OFF_WKL + WSZ;
constexpr size_t OFF_WVL = OFF_WVH + WSZ;   // UNUSED
constexpr size_t OFF_QH  = OFF_WVL + WSZ;   // [B,H,S,64]  (pre-scaled by CEXP)
constexpr size_t OFF_QL  = OFF_QH + XSZ;
constexpr size_t OFF_KH  = OFF_QL + XSZ;
constexpr size_t OFF_KL  = OFF_KH + XSZ;
constexpr size_t OFF_VH  = OFF_KL + XSZ;    // UNUSED (V-GEMM writes VT directly)
constexpr size_t OFF_VT  = OFF_VH + XSZ;    // [B,H,64,S]

// ---------------- helpers ----------------
__device__ __forceinline__ u16 f2b(float f) {           // fp32 -> bf16 RNE
  unsigned u = __builtin_bit_cast(unsigned, f);
  return (u16)((u + 0x7FFFu + ((u >> 16) & 1u)) >> 16);
}
__device__ __forceinline__ float b2f(u16 h) {
  return __builtin_bit_cast(float, ((unsigned)h) << 16);
}
__device__ __forceinline__ bf16x8 ld8(const u16* p) {   // 16B frag load
  return __builtin_bit_cast(bf16x8, *(const u32x4*)p);
}
__device__ __forceinline__ unsigned pk2(float a, float b) {  // pack 2 bf16 (RNE)
#if __has_builtin(__builtin_amdgcn_cvt_pk_bf16_f32)
  auto v = __builtin_amdgcn_cvt_pk_bf16_f32(a, b);
  return __builtin_bit_cast(unsigned, v);
#else
  return (unsigned)f2b(a) | ((unsigned)f2b(b) << 16);
#endif
}
__device__ __forceinline__ float ex2(float x) {         // raw v_exp_f32
#if __has_builtin(__builtin_amdgcn_exp2f)
  return __builtin_amdgcn_exp2f(x);
#else
  return exp2f(x);
#endif
}
__device__ __forceinline__ void glds16(const void* g, void* l) { // 16B global->LDS
  __builtin_amdgcn_global_load_lds((const glb_void*)g, (lds_void*)l, 16, 0, 0);
}
// swizzled LDS offset for a [rows][32 u16] tile: chunk = 8 u16 (16B)
__device__ __forceinline__ int swz32(int row, int cg) {
  return row * 32 + ((cg ^ ((row >> 1) & 3)) * 8);
}
// swizzled LDS offset for a [rows][64 u16] tile: chunk = 8 u16 (16B)
__device__ __forceinline__ int swz64(int row, int cg) {
  return row * 64 + ((cg ^ (row & 7)) * 8);
}

// ---------------- fused converts: x (hi/lo) + W^T (hi/lo) ----------------
// x path: 8 floats/thread (32B read, 16B hi + 16B lo store); grid 9216.
__global__ __launch_bounds__(256) void convert_all(const float* __restrict__ q,
                                                   const float* __restrict__ k,
                                                   const float* __restrict__ v,
                                                   const float* __restrict__ Wq,
                                                   const float* __restrict__ Wk,
                                                   const float* __restrict__ Wv,
                                                   u16* __restrict__ ws) {
  __shared__ float tile[32][33];
  int id = blockIdx.x;
  int t = threadIdx.x;
  if (id < 6144) {                        // ---- x path: 2048 blocks per z ----
    int z = id >> 11, blk = id & 2047;
    const float* in = (z == 0) ? q : (z == 1) ? k : v;
    u16* hi = ws + ((z == 0) ? OFF_XQH : (z == 1) ? OFF_XKH : OFF_XVH);
    u16* lo = ws + ((z == 0) ? OFF_XQL : (z == 1) ? OFF_XKL : OFF_XVL);
    size_t i = ((size_t)blk * 256u + t) * 8u;
    float4 v0 = *(const float4*)(in + i);
    float4 v1 = *(const float4*)(in + i + 4);
    float a[8] = {v0.x, v0.y, v0.z, v0.w, v1.x, v1.y, v1.z, v1.w};
    u16 hv[8], lv[8];
#pragma unroll
    for (int j = 0; j < 8; ++j) {
      u16 hb = f2b(a[j]);
      hv[j] = hb;
      lv[j] = f2b(a[j] - b2f(hb));
    }
    *(u32x4*)(hi + i) = *(const u32x4*)hv;
    if (z != 2) *(u32x4*)(lo + i) = *(const u32x4*)lv;
  } else {                                // ---- W path: 1024 blocks per z ----
    int r0 = id - 6144;
    int z = r0 >> 10, rem = r0 & 1023;
    const float* W = (z == 0) ? Wq : (z == 1) ? Wk : Wv;
    u16* hiT = ws + ((z == 0) ? OFF_WQH : (z == 1) ? OFF_WKH : OFF_WVH);
    u16* loT = ws + ((z == 0) ? OFF_WQL : (z == 1) ? OFF_WKL : OFF_WVL);
    int n0 = (rem & 31) * 32, k0 = (rem >> 5) * 32;
    int r = t >> 3, c0 = (t & 7) * 4;
    float4 vv = *(const float4*)(W + (size_t)(k0 + r) * 1024 + n0 + c0);
    tile[r][c0] = vv.x; tile[r][c0 + 1] = vv.y; tile[r][c0 + 2] = vv.z; tile[r][c0 + 3] = vv.w;
    __syncthreads();
    u16x4 hv, lv;
#pragma unroll
    for (int j = 0; j < 4; ++j) {
      float x = tile[c0 + j][r];          // = W[k0+c0+j][n0+r]
      u16 hb = f2b(x);
      hv[j] = hb;
      lv[j] = f2b(x - b2f(hb));
    }
    size_t o = (size_t)(n0 + r) * 1024 + k0 + c0;
    *(u16x4*)(hiT + o) = hv;
    if (z != 2) *(u16x4*)(loT + o) = lv;
  }
}

// ---------------- QKV projection GEMM, 128x128 tile, 4 waves -----------------
// R14 structure (glds16 staging from pre-converted bf16 ws). R18's reg-staged
// pipeline REVERTED: it put the fp32->bf16 conversion + ds_writes inside the
// barrier-locked region and regressed 110->154 us (T14 is net-negative vs
// global_load_lds on GEMM -- documented m249/m151, now re-confirmed here).
__global__ __launch_bounds__(256, 3) void gemm_qkv(u16* __restrict__ ws) {
  __shared__ u16 smem[16384];          // 32 KB: staging arrays / cbuf view
  u16* sAh = smem;                     // [128*32] each (8 KB)
  u16* sAl = smem + 4096;
  u16* sBh = smem + 8192;
  u16* sBl = smem + 12288;
  u16* cbuf = smem;                    // 128x128 u16 epilogue view (32 KB)

  int id = blockIdx.x;
  int xcd = id & 7, seq = id >> 3;          // seq 0..95
  int pair = (seq >> 3) * 8 + xcd;          // 0..95, z-balanced per XCD
  int tile_n = seq & 7;
  int z = pair >> 5;                        // 0..2
  int tile_m = pair & 31;

  const u16 *Ah, *Al, *Bh, *Bl; u16 *Oh, *Ol; bool split;
  if (z == 0)      { Ah = ws + OFF_XQH; Al = ws + OFF_XQL; Bh = ws + OFF_WQH; Bl = ws + OFF_WQL; Oh = ws + OFF_QH; Ol = ws + OFF_QL; split = true; }
  else if (z == 1) { Ah = ws + OFF_XKH; Al = ws + OFF_XKL; Bh = ws + OFF_WKH; Bl = ws + OFF_WKL; Oh = ws + OFF_KH; Ol = ws + OFF_KL; split = true; }
  else             { Ah = ws + OFF_XVH; Al = nullptr;      Bh = ws + OFF_WVH; Bl = nullptr;      Oh = ws + OFF_VT; Ol = nullptr;    split = false; }
  float oscale = (z == 0) ? CEXP : 1.0f;
  int m0 = tile_m * 128, n0 = tile_n * 128;
  int t = threadIdx.x, lane = t & 63, wave = t >> 6;
  int quad = lane >> 4, l15 = lane & 15;
  int wm = (wave >> 1) * 64, wn = (wave & 1) * 64;
  f32x4 acc[4][4] = {};

  int rt = t >> 3, ct = t & 7;              // A staging: 32 rows x 8 chunks?? (16B)
  int rl = lane >> 2, cgl = lane & 3;       // B staging: 16 rows x 4 chunks

  // staging addresses: A/B rows [i*64, i*64+64) per issue-pair
  size_t gA[2], gB[2]; int lb[2];
#pragma unroll
  for (int i = 0; i < 2; ++i) {
    int row = i * 64 + wave * 16 + rl;      // tile-local row 0..127
    int gsw = (cgl ^ ((row >> 1) & 3)) * 8;
    gA[i] = (size_t)(m0 + row) * 1024 + gsw;
    gB[i] = (size_t)(n0 + row) * 1024 + gsw;
    lb[i] = i * 2048 + wave * 512;
  }

  for (int kb = 0; kb < 32; ++kb) {
    int k0 = kb * 32;
    __syncthreads();
#pragma unroll
    for (int i = 0; i < 2; ++i) {
      glds16(Ah + gA[i] + k0, &sAh[lb[i]]);
      if (split) glds16(Al + gA[i] + k0, &sAl[lb[i]]);
      glds16(Bh + gB[i] + k0, &sBh[lb[i]]);
      if (split) glds16(Bl + gB[i] + k0, &sBl[lb[i]]);
    }
    __syncthreads();
    bf16x8 afh[4], afl[4];
#pragma unroll
    for (int mt = 0; mt < 4; ++mt) {
      int ra = wm + mt * 16 + l15;
      afh[mt] = ld8(&sAh[swz32(ra, quad)]);
      if (split) afl[mt] = ld8(&sAl[swz32(ra, quad)]);
    }
#pragma unroll
    for (int nt = 0; nt < 4; ++nt) {
      int rb = wn + nt * 16 + l15;
      bf16x8 bfh = ld8(&sBh[swz32(rb, quad)]);
      bf16x8 bfl;
      if (split) bfl = ld8(&sBl[swz32(rb, quad)]);
#pragma unroll
      for (int mt = 0; mt < 4; ++mt) {
        acc[mt][nt] = __builtin_amdgcn_mfma_f32_16x16x32_bf16(afh[mt], bfh, acc[mt][nt], 0, 0, 0);
        if (split) {
          acc[mt][nt] = __builtin_amdgcn_mfma_f32_16x16x32_bf16(afl[mt], bfh, acc[mt][nt], 0, 0, 0);
          acc[mt][nt] = __builtin_amdgcn_mfma_f32_16x16x32_bf16(afh[mt], bfl, acc[mt][nt], 0, 0, 0);
        }
      }
    }
  }
  auto epi_round = [&](u16* dst, bool lo_round) {
#pragma unroll
    for (int mt = 0; mt < 4; ++mt)
#pragma unroll
      for (int nt = 0; nt < 4; ++nt)
#pragma unroll
        for (int r = 0; r < 4; ++r) {
          int row = wm + mt * 16 + quad * 4 + r;
          int col = wn + nt * 16 + l15;
          float v = acc[mt][nt][r] * oscale;
          u16 hb = f2b(v);
          u16 val = lo_round ? f2b(v - b2f(hb)) : hb;
          cbuf[row * 128 + (((col >> 3) ^ (row & 15)) * 8) + (col & 7)] = val;
        }
    __syncthreads();
#pragma unroll
    for (int rr = 0; rr < 2; ++rr) {
      int row = rr * 64 + (t >> 2), seg = t & 3;
      int gm = m0 + row, bb = gm >> 11, s = gm & 2047;
      int hh = (n0 >> 6) + (seg >> 1), d0 = (seg & 1) * 32;
      u16* gp = dst + ((size_t)(bb * 16 + hh) * 2048 + s) * 64 + d0;
#pragma unroll
      for (int i = 0; i < 4; ++i) {
        int phys = (seg * 4 + i) ^ (row & 15);
        *(u32x4*)(gp + i * 8) = *(const u32x4*)(&cbuf[row * 128 + phys * 8]);
      }
    }
  };
  __syncthreads();                 // staging reads done; cbuf free
  if (split) {
    epi_round(Oh, false);
    __syncthreads();
    epi_round(Ol, true);
  } else {
    // ---- V: transposed epilogue, writes VT[b,h,d,s] directly ----
#pragma unroll
    for (int mt = 0; mt < 4; ++mt)
#pragma unroll
      for (int nt = 0; nt < 4; ++nt)
#pragma unroll
        for (int r = 0; r < 4; ++r) {
          int row = wm + mt * 16 + quad * 4 + r;       // seq within tile 0..127
          int col = wn + nt * 16 + l15;                // dim within 128 (2 heads)
          cbuf[row * 128 + (((col >> 3) ^ (row & 15)) * 8) + (col & 7)] =
              f2b(acc[mt][nt][r]);
        }
    __syncthreads();
    int col = t >> 1, sh = t & 1;
    int hg = (n0 + col) >> 6, d = (n0 + col) & 63;
    int bb = m0 >> 11, s0 = m0 & 2047;
#pragma unroll
    for (int part = 0; part < 2; ++part) {
      u16 vals[32];
#pragma unroll
      for (int i = 0; i < 32; ++i) {
        int row = part * 64 + sh * 32 + i;
        vals[i] = cbuf[row * 128 + (((col >> 3) ^ (row & 15)) * 8) + (col & 7)];
      }
      u16* gp = Oh + ((size_t)((bb * 16 + hg) * 64 + d)) * 2048 + s0 + part * 64 + sh * 32;
#pragma unroll
      for (int i = 0; i < 4; ++i)
        *(u32x4*)(gp + i * 8) = *(const u32x4*)(&vals[i * 8]);
    }
  }
}

// ---------------- flash attention: 64 Q-rows/block, 64-key tiles -------------
// R16 (measured 93.9 us): barriers bracket only the LDS commit; V
// double-buffered; SM+PV+next-QK unsynchronized. XCD head-grouping,
// dead-tile skip, defer-rescale, swapped PV, max3 tree, T14 reg-prefetch.
__global__ __launch_bounds__(256, 4) void attn(const u16* __restrict__ ws,
                                               float* __restrict__ out) {
  __shared__ u16 lkh[64 * 64];
  __shared__ u16 lkl[64 * 64];
  __shared__ u16 lvt[2][64 * 64];    // double-buffered V
  __shared__ u16 lp[4][16 * 64];     // per-wave P tile [qrow][key], swz64
  const u16* Qh = ws + OFF_QH; const u16* Ql = ws + OFF_QL;
  const u16* Kh = ws + OFF_KH; const u16* Kl = ws + OFF_KL;
  const u16* Vt = ws + OFF_VT;
  // ---- XCD-grouped decode: xcd owns heads [xcd*4, xcd*4+4) ----
  int id = blockIdx.x;
  int xcd = id & 7, slot = id >> 3;            // slot 0..127
  int hh = xcd * 4 + (slot >> 5);              // 0..31  (b*16+h)
  int q0 = (slot & 31) * 64;
  int b = hh >> 4, h = hh & 15;
  int t = threadIdx.x, lane = t & 63, wave = t >> 6;
  int quad = lane >> 4, l15 = lane & 15;
  size_t hb = (size_t)hh * (2048 * 64);
  bf16x8 onesf;                                  // ones A-frag for row-sum MFMA
#pragma unroll
  for (int j = 0; j < 8; ++j) onesf[j] = __builtin_bit_cast(__bf16, (u16)0x3F80);
  int qrow = q0 + wave * 16 + l15;
  bf16x8 qfh[2], qfl[2];
#pragma unroll
  for (int ks = 0; ks < 2; ++ks) {
    size_t qo = hb + (size_t)qrow * 64 + ks * 32 + quad * 8;
    qfh[ks] = ld8(Qh + qo);
    qfl[ks] = ld8(Ql + qo);
  }
  float mi = -1e30f;                 // running max for qrow=l15
  f32x4 lsum = {};                   // row-sum accumulator (all 4 regs equal)
  f32x4 o[4] = {};                   // o^T: col=l15=qrow, row=d
  int rl = lane >> 3, cgl = lane & 7;            // staging: 8 rows x 8 chunks/issue

  size_t aK[2], aV[2]; int lb[2];
#pragma unroll
  for (int i = 0; i < 2; ++i) {
    int row = wave * 16 + i * 8 + rl;            // tile-local row 0..63
    int cgg = cgl ^ (row & 7);
    aK[i] = hb + (size_t)row * 64 + cgg * 8;     // + kt*4096 in-loop
    aV[i] = hb + (size_t)row * 2048 + cgg * 8;   // + kt*64  in-loop
    lb[i] = (wave * 16 + i * 8) * 64;
  }
  int soF[2][4];
#pragma unroll
  for (int ks = 0; ks < 2; ++ks)
#pragma unroll
    for (int nt = 0; nt < 4; ++nt)
      soF[ks][nt] = swz64(nt * 16 + l15, ks * 4 + quad);
  int soP[4];
  {
    int r7 = l15 & 7;
#pragma unroll
    for (int nt = 0; nt < 4; ++nt) {
      int c = nt * 2 + (quad >> 1);
      soP[nt] = l15 * 64 + ((c ^ r7) * 8) + (quad & 1) * 4;
    }
  }
  int soPa[2];
#pragma unroll
  for (int ks = 0; ks < 2; ++ks) soPa[ks] = swz64(l15, ks * 4 + quad);
  u16* lpw = &lp[wave][0];

  // ---- prologue: stage tile 0 via global_load_lds; prefetch tile 1 regs ----
#pragma unroll
  for (int i = 0; i < 2; ++i) {
    glds16(Kh + aK[i], &lkh[lb[i]]);
    glds16(Kl + aK[i], &lkl[lb[i]]);
    glds16(Vt + aV[i], &lvt[0][lb[i]]);
  }
  u32x4 pk_[2], pl_[2], pv_[2];
#pragma unroll
  for (int i = 0; i < 2; ++i) {
    pk_[i] = *(const u32x4*)(Kh + aK[i] + 4096);
    pl_[i] = *(const u32x4*)(Kl + aK[i] + 4096);
    pv_[i] = *(const u32x4*)(Vt + aV[i] + 64);
  }
  __syncthreads();

  for (int kt = 0; kt < 32; ++kt) {
    // ---- phase A: QK^T (swapped): sc[nt] rows=keys, col=qrow=l15 ----
    f32x4 sc[4] = {};
    __builtin_amdgcn_s_setprio(1);
#pragma unroll
    for (int nt = 0; nt < 4; ++nt) {
#pragma unroll
      for (int ks = 0; ks < 2; ++ks) {
        bf16x8 kh_ = ld8(&lkh[soF[ks][nt]]);
        bf16x8 kl_ = ld8(&lkl[soF[ks][nt]]);
        sc[nt] = __builtin_amdgcn_mfma_f32_16x16x32_bf16(kh_, qfh[ks], sc[nt], 0, 0, 0);
        sc[nt] = __builtin_amdgcn_mfma_f32_16x16x32_bf16(kl_, qfh[ks], sc[nt], 0, 0, 0);
        sc[nt] = __builtin_amdgcn_mfma_f32_16x16x32_bf16(kh_, qfl[ks], sc[nt], 0, 0, 0);
      }
    }
    __builtin_amdgcn_s_setprio(0);
    // ---- barrier-locked commit (the ONLY synchronized region) ----
    __syncthreads();
    if (kt < 31) {
#pragma unroll
      for (int i = 0; i < 2; ++i) {
        *(u32x4*)(&lkh[lb[i] + lane * 8]) = pk_[i];
        *(u32x4*)(&lkl[lb[i] + lane * 8]) = pl_[i];
        *(u32x4*)(&lvt[(kt + 1) & 1][lb[i] + lane * 8]) = pv_[i];
      }
    }
    __syncthreads();
    // ---- prefetch tile kt+2 into regs (consumed at next commit) ----
    if (kt < 30) {
#pragma unroll
      for (int i = 0; i < 2; ++i) {
        pk_[i] = *(const u32x4*)(Kh + aK[i] + (kt + 2) * 4096);
        pl_[i] = *(const u32x4*)(Kl + aK[i] + (kt + 2) * 4096);
        pv_[i] = *(const u32x4*)(Vt + aV[i] + (kt + 2) * 64);
      }
    }
    // ---- phase B (unsynchronized): softmax + PV on lvt[kt&1] ----
    float t0 = fmaxf(fmaxf(sc[0][0], sc[0][1]), sc[0][2]);
    float t1 = fmaxf(fmaxf(sc[0][3], sc[1][0]), sc[1][1]);
    float t2 = fmaxf(fmaxf(sc[1][2], sc[1][3]), sc[2][0]);
    float t3 = fmaxf(fmaxf(sc[2][1], sc[2][2]), sc[2][3]);
    float t4 = fmaxf(fmaxf(sc[3][0], sc[3][1]), sc[3][2]);
    float mx = fmaxf(fmaxf(fmaxf(t0, t1), fmaxf(t2, t3)), fmaxf(t4, sc[3][3]));
    mx = fmaxf(mx, __shfl_xor(mx, 16));
    mx = fmaxf(mx, __shfl_xor(mx, 32));
    float mi_old = mi;
    unsigned long long live = __ballot(mx > mi_old - 28.0f);
    float mn = fmaxf(mi_old, mx);
    mi = mn;
    if (live) {
      unsigned long long grew = __ballot(mx > mi_old);   // wave-uniform
      // ---- P = exp2(sc - mn), packed ds_write_b64 into lp[qrow][key] ----
#pragma unroll
      for (int nt = 0; nt < 4; ++nt) {
        unsigned u01 = pk2(ex2(sc[nt][0] - mn), ex2(sc[nt][1] - mn));
        unsigned u23 = pk2(ex2(sc[nt][2] - mn), ex2(sc[nt][3] - mn));
        *(u32x2*)(&lpw[soP[nt]]) = u32x2{u01, u23};
      }
      // ---- rescale (alpha per-lane: qrow=l15 domain) ----
      if (grew) {
        float a = ex2(mi_old - mn);
#pragma unroll
        for (int r = 0; r < 4; ++r) {
          lsum[r] *= a;
          o[0][r] *= a; o[1][r] *= a; o[2][r] *= a; o[3][r] *= a;
        }
      }
      // wave-private LDS write->read: drain DS queue (in-order per wave)
      asm volatile("s_waitcnt lgkmcnt(0)" ::: "memory");
      // ---- swapped PV: o^T += V-frag (A) x P (B); lsum via ones-A ----
      bf16x8 pa[2];
#pragma unroll
      for (int ks = 0; ks < 2; ++ks) pa[ks] = ld8(&lpw[soPa[ks]]);
      __builtin_amdgcn_s_setprio(1);
      lsum = __builtin_amdgcn_mfma_f32_16x16x32_bf16(onesf, pa[0], lsum, 0, 0, 0);
      lsum = __builtin_amdgcn_mfma_f32_16x16x32_bf16(onesf, pa[1], lsum, 0, 0, 0);
      const u16* lv = &lvt[kt & 1][0];
#pragma unroll
      for (int nt = 0; nt < 4; ++nt)
#pragma unroll
        for (int ks = 0; ks < 2; ++ks) {
          bf16x8 bv = ld8(&lv[soF[ks][nt]]);
          o[nt] = __builtin_amdgcn_mfma_f32_16x16x32_bf16(bv, pa[ks], o[nt], 0, 0, 0);
        }
      __builtin_amdgcn_s_setprio(0);
    }
  }
  // epilogue: o^T -> out[b, qrow, h*64 + d], contiguous f32x4 per (nt,quad)
  float inv = 1.0f / lsum[0];
  float* op = out + (size_t)(b * 2048 + q0 + wave * 16 + l15) * 1024 + h * 64;
#pragma unroll
  for (int nt = 0; nt < 4; ++nt) {
    f32x4 w;
#pragma unroll
    for (int r = 0; r < 4; ++r) w[r] = o[nt][r] * inv;
    *(f32x4*)(op + nt * 16 + quad * 4) = w;
  }
}

extern "C" void kernel_launch(void* const* d_in, const int* in_sizes, int n_in,
                              void* d_out, int out_size, void* d_ws, size_t ws_size,
                              hipStream_t stream) {
  const float* q  = (const float*)d_in[0];
  const float* k  = (const float*)d_in[1];
  const float* v  = (const float*)d_in[2];
  const float* Wq = (const float*)d_in[3];
  const float* Wk = (const float*)d_in[4];
  const float* Wv = (const float*)d_in[5];
  u16* ws = (u16*)d_ws;
  float* out = (float*)d_out;

  convert_all<<<9216, 256, 0, stream>>>(q, k, v, Wq, Wk, Wv, ws);
  gemm_qkv<<<768, 256, 0, stream>>>(ws);
  attn<<<1024, 256, 0, stream>>>(ws, out);
}